// Round 8
// baseline (609.141 us; speedup 1.0000x reference)
//
#include <hip/hip_runtime.h>
#include <hip/hip_bf16.h>
#include <math.h>

#define DIM      512
#define D_STATE  16
#define D_CONV   4
#define D_INNER  1024
#define DT_RANK  32
#define B_SZ     2
#define SEQ      2048
#define NTOK     (B_SZ * SEQ)   // 4096
#define CHUNK    128
#define NCH      (SEQ / CHUNK)  // 16
#define NC_PAD   1152           // 1024 dt + 32 BC + 96 pad
#define PG       8              // scan pipeline group size
#define NPG      (CHUNK / PG)   // 16

typedef __attribute__((ext_vector_type(8))) short bf16x8;
typedef __attribute__((ext_vector_type(4))) float f32x4;

__device__ __forceinline__ short f2bf(float f) {
    unsigned u = __float_as_uint(f);
    u += 0x7fffu + ((u >> 16) & 1u);
    return (short)(u >> 16);
}

// ---------------- MFMA GEMM: C[M,N] (+)= alpha * A[M,K] @ W[N,K]^T ----------
// 64x64 tile, BK=32, 256 thr = 4 waves (2x2), each wave 32x32 (2x2 frags of
// 16x16x32). Small tile -> 512..2048 blocks/dispatch (2-8 per CU) so the
// latency of fp32->bf16 staging is hidden by TLP, not serialized per block.
// LDS chunk layout: chunk ci = mblk*64 + kc*16 + ml -> elem (m=mblk*16+ml,
// k=kc*8..+8); thread tid stages chunk tid; frag reads are lane-contiguous.
#define GTM 64
#define GTN 64
#define GTK 32

__global__ __launch_bounds__(256)
void gemm_mfma(const float* __restrict__ A, int lda,
               const float* __restrict__ W, int ldw,
               float* __restrict__ C, int ldc,
               int K, float alpha, int accum)
{
    __shared__ __align__(16) short As[GTM * GTK];
    __shared__ __align__(16) short Ws[GTN * GTK];

    const int tid  = threadIdx.x;
    const int lane = tid & 63;
    const int wid  = tid >> 6;
    const int wr   = wid >> 1, wc = wid & 1;
    const int m0 = blockIdx.y * GTM;
    const int n0 = blockIdx.x * GTN;

    // staging: thread tid -> chunk tid: m = (tid>>6)*16 + (tid&15), kc = (tid>>4)&3
    const int am = ((tid >> 6) << 4) | (tid & 15);
    const int kc = (tid >> 4) & 3;
    const float* pa = A + (size_t)(m0 + am) * lda + kc * 8;
    const float* pw = W + (size_t)(n0 + am) * ldw + kc * 8;

    f32x4 acc[2][2] = {};

    for (int k0 = 0; k0 < K; k0 += GTK) {
        {
            float4 a0 = *(const float4*)(pa + k0);
            float4 a1 = *(const float4*)(pa + k0 + 4);
            float4 b0 = *(const float4*)(pw + k0);
            float4 b1 = *(const float4*)(pw + k0 + 4);
            bf16x8 va, vb;
            va[0] = f2bf(a0.x); va[1] = f2bf(a0.y); va[2] = f2bf(a0.z); va[3] = f2bf(a0.w);
            va[4] = f2bf(a1.x); va[5] = f2bf(a1.y); va[6] = f2bf(a1.z); va[7] = f2bf(a1.w);
            vb[0] = f2bf(b0.x); vb[1] = f2bf(b0.y); vb[2] = f2bf(b0.z); vb[3] = f2bf(b0.w);
            vb[4] = f2bf(b1.x); vb[5] = f2bf(b1.y); vb[6] = f2bf(b1.z); vb[7] = f2bf(b1.w);
            *(bf16x8*)(As + tid * 8) = va;
            *(bf16x8*)(Ws + tid * 8) = vb;
        }
        __syncthreads();

        bf16x8 af[2], bff[2];
#pragma unroll
        for (int f = 0; f < 2; ++f) {
            int ai = (wr * 2 + f) * 64 + (lane >> 4) * 16 + (lane & 15);
            af[f]  = *(const bf16x8*)(As + ai * 8);
            int bi = (wc * 2 + f) * 64 + (lane >> 4) * 16 + (lane & 15);
            bff[f] = *(const bf16x8*)(Ws + bi * 8);
        }
#pragma unroll
        for (int i = 0; i < 2; ++i)
#pragma unroll
            for (int j = 0; j < 2; ++j)
                acc[i][j] = __builtin_amdgcn_mfma_f32_16x16x32_bf16(
                    af[i], bff[j], acc[i][j], 0, 0, 0);
        __syncthreads();
    }

#pragma unroll
    for (int i = 0; i < 2; ++i) {
        int row = m0 + wr * 32 + i * 16 + ((lane >> 4) << 2);
#pragma unroll
        for (int j = 0; j < 2; ++j) {
            int col = n0 + wc * 32 + j * 16 + (lane & 15);
#pragma unroll
            for (int r = 0; r < 4; ++r) {
                float v = alpha * acc[i][j][r];
                float* p = &C[(size_t)(row + r) * ldc + col];
                if (accum) *p += v; else *p = v;
            }
        }
    }
}

// ---------------- combined projection weight -----------------------------
__global__ __launch_bounds__(256)
void build_wc(const float* __restrict__ xproj_w,  // [64,1024]
              const float* __restrict__ dt_w,     // [1024,32]
              float* __restrict__ Wc)             // [1152,1024]
{
    int idx = blockIdx.x * 256 + threadIdx.x;
    if (idx >= NC_PAD * D_INNER) return;
    int i = idx >> 10, k = idx & 1023;
    float v;
    if (i < 1024) {
        v = 0.f;
#pragma unroll
        for (int r = 0; r < 32; ++r)
            v = fmaf(dt_w[i * 32 + r], xproj_w[r * 1024 + k], v);
    } else if (i < 1056) {
        v = xproj_w[(i - 1024 + 32) * 1024 + k];
    } else {
        v = 0.f;
    }
    Wc[idx] = v;
}

// ---------------- depthwise causal conv (k=4) + bias + SiLU --------------
__global__ __launch_bounds__(256)
void conv_silu_kernel(const float* __restrict__ xz,
                      const float* __restrict__ cw,
                      const float* __restrict__ cb,
                      float* __restrict__ xc, int rev)
{
    int idx = blockIdx.x * 256 + threadIdx.x;
    if (idx >= NTOK * D_INNER) return;
    int c   = idx & (D_INNER - 1);
    int row = idx >> 10;
    int b   = row / SEQ;
    int u   = row - b * SEQ;

    float w0 = cw[c * 4 + 0], w1 = cw[c * 4 + 1];
    float w2 = cw[c * 4 + 2], w3 = cw[c * 4 + 3];
    float accv = cb[c];
    if (!rev) {
#pragma unroll
        for (int k = 0; k < 4; ++k) {
            int uu = u - 3 + k;
            float wv = (k == 0) ? w0 : (k == 1) ? w1 : (k == 2) ? w2 : w3;
            if (uu >= 0)
                accv = fmaf(wv, xz[(size_t)(b * SEQ + uu) * (2 * D_INNER) + c], accv);
        }
    } else {
#pragma unroll
        for (int k = 0; k < 4; ++k) {
            int uu = u + 3 - k;
            float wv = (k == 0) ? w0 : (k == 1) ? w1 : (k == 2) ? w2 : w3;
            if (uu < SEQ)
                accv = fmaf(wv, xz[(size_t)(b * SEQ + uu) * (2 * D_INNER) + c], accv);
        }
    }
    xc[idx] = accv / (1.f + expf(-accv));
}

// ---------------- dt bias + softplus (in place, strided) -----------------
__global__ __launch_bounds__(256)
void bias_softplus_kernel(float* __restrict__ xdblP, const float* __restrict__ dtb)
{
    int idx = blockIdx.x * 256 + threadIdx.x;
    if (idx >= NTOK * D_INNER) return;
    int c = idx & (D_INNER - 1);
    int row = idx >> 10;
    float* p = &xdblP[(size_t)row * NC_PAD + c];
    float v = *p + dtb[c];
    *p = (v > 20.f) ? v : log1pf(expf(v));
}

// ---------------- chunked SSM scan: one thread per channel, h[16] in regs --
// grid: b (2) x ch (NCH) x cb (4); c = cb*256 + tid.
// summaries: chP/chH/hst[((b*NCH+ch)*1024 + c)*16 + s]
// Software pipeline: register double-buffer of PG=8 tokens' {dt,xc[,z]} so
// ~16-24 loads stay in flight while the previous group's exp2/fma chain runs.

__global__ __launch_bounds__(256)
void scan_p1(const float* __restrict__ xdblP,
             const float* __restrict__ xc,
             const float* __restrict__ A_log,
             float* __restrict__ chP,
             float* __restrict__ chH, int rev)
{
    __shared__ float Bs[CHUNK][16];
    const int tid = threadIdx.x;
    const int blk = blockIdx.x;
    const int cb = blk & 3;
    const int ch = (blk >> 2) & (NCH - 1);
    const int b  = blk >> 6;             // 4*NCH = 64 blocks per batch
    const int c  = cb * 256 + tid;

    const int u0 = rev ? (SEQ - 1 - ch * CHUNK) : (ch * CHUNK);
    const int st = rev ? -1 : 1;

    for (int r = tid; r < CHUNK * 16; r += 256) {
        int i = r >> 4, s = r & 15;
        int row = b * SEQ + u0 + st * i;
        Bs[i][s] = xdblP[(size_t)row * NC_PAD + 1024 + s];
    }

    float Acs[16];
#pragma unroll
    for (int s = 0; s < 16; ++s)
        Acs[s] = -__expf(A_log[c * 16 + s]) * 1.44269504f;  // fold log2(e)

    float h[16], P[16];
#pragma unroll
    for (int s = 0; s < 16; ++s) { h[s] = 0.f; P[s] = 1.f; }

    __syncthreads();

    const float* dtp = xdblP + (size_t)(b * SEQ + u0) * NC_PAD + c;
    const float* xcp = xc    + (size_t)(b * SEQ + u0) * D_INNER + c;
    const ptrdiff_t dstep = (ptrdiff_t)st * NC_PAD;
    const ptrdiff_t xstep = (ptrdiff_t)st * D_INNER;

    float dt_r[PG], xc_r[PG];
#pragma unroll
    for (int j = 0; j < PG; ++j) {
        dt_r[j] = dtp[dstep * j];
        xc_r[j] = xcp[xstep * j];
    }

#pragma unroll 1
    for (int g = 0; g < NPG; ++g) {
        // prefetch next group (clamped on last iteration; redundant but valid)
        const int gg = (g + 1 < NPG) ? (g + 1) : g;
        float dt_n[PG], xc_n[PG];
#pragma unroll
        for (int j = 0; j < PG; ++j) {
            int i = gg * PG + j;
            dt_n[j] = dtp[dstep * i];
            xc_n[j] = xcp[xstep * i];
        }
        // compute current group
#pragma unroll
        for (int j = 0; j < PG; ++j) {
            int i = g * PG + j;
            float dtv = dt_r[j];
            float e = dtv * xc_r[j];
#pragma unroll
            for (int s = 0; s < 16; ++s) {
                float da = __builtin_amdgcn_exp2f(dtv * Acs[s]);
                h[s] = fmaf(da, h[s], e * Bs[i][s]);
                P[s] *= da;
            }
        }
#pragma unroll
        for (int j = 0; j < PG; ++j) { dt_r[j] = dt_n[j]; xc_r[j] = xc_n[j]; }
    }

    size_t o = ((size_t)(b * NCH + ch) * 1024 + c) * 16;
#pragma unroll
    for (int q = 0; q < 4; ++q) {
        *(float4*)&chP[o + q * 4] = make_float4(P[q*4], P[q*4+1], P[q*4+2], P[q*4+3]);
        *(float4*)&chH[o + q * 4] = make_float4(h[q*4], h[q*4+1], h[q*4+2], h[q*4+3]);
    }
}

// scan over chunk summaries -> hst (separate output, no in-place rewrite)
__global__ __launch_bounds__(256)
void scan_p2(const float* __restrict__ chP,
             const float* __restrict__ chH,
             float* __restrict__ hst)
{
    int idx = blockIdx.x * 256 + threadIdx.x;   // B_SZ*16384
    int b  = idx >> 14;
    int cs = idx & 16383;
    float h = 0.f;
#pragma unroll
    for (int ch = 0; ch < NCH; ++ch) {
        size_t o = ((size_t)(b * NCH + ch) << 14) + cs;
        hst[o] = h;
        h = fmaf(chP[o], h, chH[o]);
    }
}

__global__ __launch_bounds__(256)
void scan_p3(const float* __restrict__ xdblP,
             const float* __restrict__ xc,
             const float* __restrict__ xz,    // z at col 1024+c (read only)
             const float* __restrict__ A_log,
             const float* __restrict__ Dp,
             const float* __restrict__ hst,
             float* __restrict__ ybar, int rev)
{
    __shared__ float Bs[CHUNK][16];
    __shared__ float Cs[CHUNK][16];
    const int tid = threadIdx.x;
    const int blk = blockIdx.x;
    const int cb = blk & 3;
    const int ch = (blk >> 2) & (NCH - 1);
    const int b  = blk >> 6;
    const int c  = cb * 256 + tid;

    const int u0 = rev ? (SEQ - 1 - ch * CHUNK) : (ch * CHUNK);
    const int st = rev ? -1 : 1;

    for (int r = tid; r < CHUNK * 16; r += 256) {
        int i = r >> 4, s = r & 15;
        int row = b * SEQ + u0 + st * i;
        Bs[i][s] = xdblP[(size_t)row * NC_PAD + 1024 + s];
        Cs[i][s] = xdblP[(size_t)row * NC_PAD + 1040 + s];
    }

    float Acs[16];
#pragma unroll
    for (int s = 0; s < 16; ++s)
        Acs[s] = -__expf(A_log[c * 16 + s]) * 1.44269504f;

    const float Dc = Dp[c];

    float h[16];
    size_t o = ((size_t)(b * NCH + ch) * 1024 + c) * 16;
#pragma unroll
    for (int q = 0; q < 4; ++q) {
        float4 hv = *(const float4*)&hst[o + q * 4];
        h[q*4] = hv.x; h[q*4+1] = hv.y; h[q*4+2] = hv.z; h[q*4+3] = hv.w;
    }

    __syncthreads();

    const float* dtp = xdblP + (size_t)(b * SEQ + u0) * NC_PAD + c;
    const float* xcp = xc    + (size_t)(b * SEQ + u0) * D_INNER + c;
    const float* zp  = xz    + (size_t)(b * SEQ + u0) * (2 * D_INNER) + D_INNER + c;
    float*       yp  = ybar  + (size_t)(b * SEQ + u0) * D_INNER + c;
    const ptrdiff_t dstep = (ptrdiff_t)st * NC_PAD;
    const ptrdiff_t xstep = (ptrdiff_t)st * D_INNER;
    const ptrdiff_t zstep = (ptrdiff_t)st * 2 * D_INNER;

    float dt_r[PG], xc_r[PG], z_r[PG];
#pragma unroll
    for (int j = 0; j < PG; ++j) {
        dt_r[j] = dtp[dstep * j];
        xc_r[j] = xcp[xstep * j];
        z_r[j]  = zp[zstep * j];
    }

#pragma unroll 1
    for (int g = 0; g < NPG; ++g) {
        const int gg = (g + 1 < NPG) ? (g + 1) : g;
        float dt_n[PG], xc_n[PG], z_n[PG];
#pragma unroll
        for (int j = 0; j < PG; ++j) {
            int i = gg * PG + j;
            dt_n[j] = dtp[dstep * i];
            xc_n[j] = xcp[xstep * i];
            z_n[j]  = zp[zstep * i];
        }
#pragma unroll
        for (int j = 0; j < PG; ++j) {
            int i = g * PG + j;
            float dtv = dt_r[j];
            float xcv = xc_r[j];
            float e = dtv * xcv;
            float y = 0.f;
#pragma unroll
            for (int s = 0; s < 16; ++s) {
                float da = __builtin_amdgcn_exp2f(dtv * Acs[s]);
                h[s] = fmaf(da, h[s], e * Bs[i][s]);
                y = fmaf(h[s], Cs[i][s], y);
            }
            y = fmaf(Dc, xcv, y);
            float zv = z_r[j];
            float sig = 1.f / (1.f + __expf(-zv));
            yp[xstep * i] = y * zv * sig;
        }
#pragma unroll
        for (int j = 0; j < PG; ++j) {
            dt_r[j] = dt_n[j]; xc_r[j] = xc_n[j]; z_r[j] = z_n[j];
        }
    }
}

extern "C" void kernel_launch(void* const* d_in, const int* in_sizes, int n_in,
                              void* d_out, int out_size, void* d_ws, size_t ws_size,
                              hipStream_t stream)
{
    const float* x = (const float*)d_in[0];
    float* out = (float*)d_out;
    float* ws  = (float*)d_ws;

    // workspace layout (floats), reused across directions (92.27 MB — proven):
    float* xz    = ws;                                    // 8,388,608
    float* xc    = xz    + (size_t)NTOK * 2 * D_INNER;    // 4,194,304
    float* xdblP = xc    + (size_t)NTOK * D_INNER;        // 4,718,592
    float* ybar  = xdblP + (size_t)NTOK * NC_PAD;         // 4,194,304
    float* chP   = ybar  + (size_t)NTOK * D_INNER;        // 524,288
    float* chH   = chP   + (size_t)B_SZ * NCH * D_INNER * D_STATE;
    float* hst   = chH   + (size_t)B_SZ * NCH * D_INNER * D_STATE;
    float* Wc    = chP;  // alias: Wc (1.18M floats, spans chP/chH/part of hst)
                         // consumed by GEMM2 before scan_p1/p2 overwrite them

    const int elemN = NTOK * D_INNER;
    const int gElem = (elemN + 255) / 256;
    const int gScan = B_SZ * NCH * 4;   // 128 blocks

    for (int dir = 0; dir < 2; ++dir) {
        const float* in_w    = (const float*)d_in[1 + dir * 9 + 0];
        const float* conv_w  = (const float*)d_in[1 + dir * 9 + 1];
        const float* conv_b  = (const float*)d_in[1 + dir * 9 + 2];
        const float* xproj_w = (const float*)d_in[1 + dir * 9 + 3];
        const float* dt_w    = (const float*)d_in[1 + dir * 9 + 4];
        const float* dt_b    = (const float*)d_in[1 + dir * 9 + 5];
        const float* A_log   = (const float*)d_in[1 + dir * 9 + 6];
        const float* Dp      = (const float*)d_in[1 + dir * 9 + 7];
        const float* out_w   = (const float*)d_in[1 + dir * 9 + 8];

        // 0) combined projection weight Wc = [dt_w @ xproj_w[:32]; xproj_w[32:64]; 0]
        build_wc<<<(NC_PAD * D_INNER + 255) / 256, 256, 0, stream>>>(
            xproj_w, dt_w, Wc);

        // 1) xz = x @ in_w.T   [4096, 2048]  — grid 32x64 = 2048 blocks
        {
            dim3 g(2 * D_INNER / GTN, NTOK / GTM);
            gemm_mfma<<<g, 256, 0, stream>>>(x, DIM, in_w, DIM,
                                             xz, 2 * D_INNER, DIM, 1.f, 0);
        }
        // 2) conv + silu -> xc
        conv_silu_kernel<<<gElem, 256, 0, stream>>>(xz, conv_w, conv_b, xc, dir);
        // 3+4) xdblP = xc @ Wc.T  [4096, 1152] — grid 18x64 = 1152 blocks
        {
            dim3 g(NC_PAD / GTN, NTOK / GTM);
            gemm_mfma<<<g, 256, 0, stream>>>(xc, D_INNER, Wc, D_INNER,
                                             xdblP, NC_PAD, D_INNER, 1.f, 0);
        }
        // 5) dt = softplus(dt_pre + dt_b)  (in place, cols 0..1023)
        bias_softplus_kernel<<<gElem, 256, 0, stream>>>(xdblP, dt_b);
        // 6) chunked scan -> ybar
        scan_p1<<<gScan, 256, 0, stream>>>(xdblP, xc, A_log, chP, chH, dir);
        scan_p2<<<(B_SZ * 16384) / 256, 256, 0, stream>>>(chP, chH, hst);
        scan_p3<<<gScan, 256, 0, stream>>>(xdblP, xc, xz, A_log, Dp, hst,
                                           ybar, dir);
        // 7) out (+)= 0.5 * ybar @ out_w.T   [4096, 512] — grid 8x64 = 512 blocks
        {
            dim3 g(DIM / GTN, NTOK / GTM);
            gemm_mfma<<<g, 256, 0, stream>>>(ybar, D_INNER, out_w, D_INNER,
                                             out, DIM, D_INNER, 0.5f, dir);
        }
    }
}

// Round 9
// 465.205 us; speedup vs baseline: 1.3094x; 1.3094x over previous
//
#include <hip/hip_runtime.h>
#include <hip/hip_bf16.h>
#include <math.h>

#define DIM      512
#define D_STATE  16
#define D_CONV   4
#define D_INNER  1024
#define DT_RANK  32
#define B_SZ     2
#define SEQ      2048
#define NTOK     (B_SZ * SEQ)   // 4096
#define CHUNK    128
#define NCH      (SEQ / CHUNK)  // 16
#define NC_PAD   1152           // 1024 dt + 32 BC + 96 pad
#define PG       8              // scan pipeline group size
#define NPG      (CHUNK / PG)   // 16

typedef __attribute__((ext_vector_type(8))) short bf16x8;
typedef __attribute__((ext_vector_type(4))) float f32x4;

__device__ __forceinline__ short f2bf(float f) {
    unsigned u = __float_as_uint(f);
    u += 0x7fffu + ((u >> 16) & 1u);
    return (short)(u >> 16);
}

// async global->LDS, 16B per lane; LDS dest is wave-uniform base + lane*16
__device__ __forceinline__ void gload16(const void* g, void* l) {
    __builtin_amdgcn_global_load_lds(
        (const __attribute__((address_space(1))) void*)g,
        (__attribute__((address_space(3))) void*)l,
        16, 0, 0);
}

// ---------------- fp32 -> bf16 bulk convert (n % 8 == 0) ------------------
__global__ __launch_bounds__(256)
void cvt_bf16(const float* __restrict__ src, short* __restrict__ dst, int n)
{
    int i = (blockIdx.x * 256 + threadIdx.x) * 8;
    if (i >= n) return;
    float4 a = *(const float4*)(src + i);
    float4 b = *(const float4*)(src + i + 4);
    bf16x8 v;
    v[0] = f2bf(a.x); v[1] = f2bf(a.y); v[2] = f2bf(a.z); v[3] = f2bf(a.w);
    v[4] = f2bf(b.x); v[5] = f2bf(b.y); v[6] = f2bf(b.z); v[7] = f2bf(b.w);
    *(bf16x8*)(dst + i) = v;
}

// ---------------- MFMA GEMM (bf16 operands): C (+)= alpha * A @ W^T ---------
// A [M,K] bf16 row-major, W [N,K] bf16 row-major, C fp32 [M,ldc].
// 128x128 tile, BK=32, 4 waves (2x2), wave tile 64x64 (4x4 frags 16x16x32).
// Staging: global_load_lds dwordx4, double-buffered LDS; stage t+1 while
// computing t (T3-minimum 2-phase schedule).
// LDS chunk ci = mblk*64 + kc*16 + ml (16B chunks); staging order ci =
// q*256 + wid*64 + lane is lane-contiguous per wave as HW requires.
#define TM 128
#define TN 128
#define TK 32

__global__ __launch_bounds__(256)
void gemm_bf16(const short* __restrict__ A, int lda,
               const short* __restrict__ W, int ldw,
               float* __restrict__ C, int ldc,
               int K, float alpha, int accum)
{
    __shared__ __align__(16) short As[2][TM * TK];
    __shared__ __align__(16) short Ws[2][TN * TK];

    const int tid  = threadIdx.x;
    const int lane = tid & 63;
    const int wid  = tid >> 6;
    const int wr   = wid >> 1, wc = wid & 1;
    const int m0 = blockIdx.y * TM;
    const int n0 = blockIdx.x * TN;

    // ci0 = tid -> am0, kc0 ; ci1 = tid+256 -> am0+64, kc0
    const int am0 = ((tid >> 6) << 4) | (tid & 15);
    const int kc0 = (tid >> 4) & 3;
    const short* pa0 = A + (size_t)(m0 + am0) * lda + kc0 * 8;
    const short* pa1 = pa0 + (size_t)64 * lda;
    const short* pw0 = W + (size_t)(n0 + am0) * ldw + kc0 * 8;
    const short* pw1 = pw0 + (size_t)64 * ldw;

    f32x4 acc[4][4] = {};
    const int nt = K / TK;

    // prologue: stage tile 0
    gload16(pa0, &As[0][tid * 8]);
    gload16(pa1, &As[0][(tid + 256) * 8]);
    gload16(pw0, &Ws[0][tid * 8]);
    gload16(pw1, &Ws[0][(tid + 256) * 8]);
    asm volatile("s_waitcnt vmcnt(0)" ::: "memory");
    __syncthreads();

    int cur = 0;
    for (int t = 0; t < nt; ++t) {
        if (t + 1 < nt) {
            const int off = (t + 1) * TK;
            gload16(pa0 + off, &As[cur ^ 1][tid * 8]);
            gload16(pa1 + off, &As[cur ^ 1][(tid + 256) * 8]);
            gload16(pw0 + off, &Ws[cur ^ 1][tid * 8]);
            gload16(pw1 + off, &Ws[cur ^ 1][(tid + 256) * 8]);
        }
        bf16x8 af[4], bff[4];
#pragma unroll
        for (int f = 0; f < 4; ++f) {
            int ai = (wr * 4 + f) * 64 + (lane >> 4) * 16 + (lane & 15);
            af[f]  = *(const bf16x8*)(&As[cur][ai * 8]);
            int bi = (wc * 4 + f) * 64 + (lane >> 4) * 16 + (lane & 15);
            bff[f] = *(const bf16x8*)(&Ws[cur][bi * 8]);
        }
#pragma unroll
        for (int i = 0; i < 4; ++i)
#pragma unroll
            for (int j = 0; j < 4; ++j)
                acc[i][j] = __builtin_amdgcn_mfma_f32_16x16x32_bf16(
                    af[i], bff[j], acc[i][j], 0, 0, 0);
        asm volatile("s_waitcnt vmcnt(0)" ::: "memory");
        __syncthreads();
        cur ^= 1;
    }

#pragma unroll
    for (int i = 0; i < 4; ++i) {
        int row = m0 + wr * 64 + i * 16 + ((lane >> 4) << 2);
#pragma unroll
        for (int j = 0; j < 4; ++j) {
            int col = n0 + wc * 64 + j * 16 + (lane & 15);
#pragma unroll
            for (int r = 0; r < 4; ++r) {
                float v = alpha * acc[i][j][r];
                float* p = &C[(size_t)(row + r) * ldc + col];
                if (accum) *p += v; else *p = v;
            }
        }
    }
}

// ---------------- combined projection weight (bf16 out) ------------------
__global__ __launch_bounds__(256)
void build_wc(const float* __restrict__ xproj_w,  // [64,1024]
              const float* __restrict__ dt_w,     // [1024,32]
              short* __restrict__ Wcb)            // [1152,1024] bf16
{
    int idx = blockIdx.x * 256 + threadIdx.x;
    if (idx >= NC_PAD * D_INNER) return;
    int i = idx >> 10, k = idx & 1023;
    float v;
    if (i < 1024) {
        v = 0.f;
#pragma unroll
        for (int r = 0; r < 32; ++r)
            v = fmaf(dt_w[i * 32 + r], xproj_w[r * 1024 + k], v);
    } else if (i < 1056) {
        v = xproj_w[(i - 1024 + 32) * 1024 + k];
    } else {
        v = 0.f;
    }
    Wcb[idx] = f2bf(v);
}

// ---------------- depthwise causal conv (k=4) + bias + SiLU --------------
// writes fp32 xc (for scan) and bf16 xcb (GEMM2 operand)
__global__ __launch_bounds__(256)
void conv_silu_kernel(const float* __restrict__ xz,
                      const float* __restrict__ cw,
                      const float* __restrict__ cb,
                      float* __restrict__ xc,
                      short* __restrict__ xcb, int rev)
{
    int idx = blockIdx.x * 256 + threadIdx.x;
    if (idx >= NTOK * D_INNER) return;
    int c   = idx & (D_INNER - 1);
    int row = idx >> 10;
    int b   = row / SEQ;
    int u   = row - b * SEQ;

    float w0 = cw[c * 4 + 0], w1 = cw[c * 4 + 1];
    float w2 = cw[c * 4 + 2], w3 = cw[c * 4 + 3];
    float accv = cb[c];
    if (!rev) {
#pragma unroll
        for (int k = 0; k < 4; ++k) {
            int uu = u - 3 + k;
            float wv = (k == 0) ? w0 : (k == 1) ? w1 : (k == 2) ? w2 : w3;
            if (uu >= 0)
                accv = fmaf(wv, xz[(size_t)(b * SEQ + uu) * (2 * D_INNER) + c], accv);
        }
    } else {
#pragma unroll
        for (int k = 0; k < 4; ++k) {
            int uu = u + 3 - k;
            float wv = (k == 0) ? w0 : (k == 1) ? w1 : (k == 2) ? w2 : w3;
            if (uu < SEQ)
                accv = fmaf(wv, xz[(size_t)(b * SEQ + uu) * (2 * D_INNER) + c], accv);
        }
    }
    float r = accv / (1.f + expf(-accv));
    xc[idx] = r;
    xcb[idx] = f2bf(r);
}

// ---------------- dt bias + softplus (in place, strided) -----------------
__global__ __launch_bounds__(256)
void bias_softplus_kernel(float* __restrict__ xdblP, const float* __restrict__ dtb)
{
    int idx = blockIdx.x * 256 + threadIdx.x;
    if (idx >= NTOK * D_INNER) return;
    int c = idx & (D_INNER - 1);
    int row = idx >> 10;
    float* p = &xdblP[(size_t)row * NC_PAD + c];
    float v = *p + dtb[c];
    *p = (v > 20.f) ? v : log1pf(expf(v));
}

// ---------------- chunked SSM scan: one thread per channel, h[16] in regs --
__global__ __launch_bounds__(256)
void scan_p1(const float* __restrict__ xdblP,
             const float* __restrict__ xc,
             const float* __restrict__ A_log,
             float* __restrict__ chP,
             float* __restrict__ chH, int rev)
{
    __shared__ float Bs[CHUNK][16];
    const int tid = threadIdx.x;
    const int blk = blockIdx.x;
    const int cb = blk & 3;
    const int ch = (blk >> 2) & (NCH - 1);
    const int b  = blk >> 6;
    const int c  = cb * 256 + tid;

    const int u0 = rev ? (SEQ - 1 - ch * CHUNK) : (ch * CHUNK);
    const int st = rev ? -1 : 1;

    for (int r = tid; r < CHUNK * 16; r += 256) {
        int i = r >> 4, s = r & 15;
        int row = b * SEQ + u0 + st * i;
        Bs[i][s] = xdblP[(size_t)row * NC_PAD + 1024 + s];
    }

    float Acs[16];
#pragma unroll
    for (int s = 0; s < 16; ++s)
        Acs[s] = -__expf(A_log[c * 16 + s]) * 1.44269504f;

    float h[16], P[16];
#pragma unroll
    for (int s = 0; s < 16; ++s) { h[s] = 0.f; P[s] = 1.f; }

    __syncthreads();

    const float* dtp = xdblP + (size_t)(b * SEQ + u0) * NC_PAD + c;
    const float* xcp = xc    + (size_t)(b * SEQ + u0) * D_INNER + c;
    const ptrdiff_t dstep = (ptrdiff_t)st * NC_PAD;
    const ptrdiff_t xstep = (ptrdiff_t)st * D_INNER;

    float dt_r[PG], xc_r[PG];
#pragma unroll
    for (int j = 0; j < PG; ++j) {
        dt_r[j] = dtp[dstep * j];
        xc_r[j] = xcp[xstep * j];
    }

#pragma unroll 1
    for (int g = 0; g < NPG; ++g) {
        const int gg = (g + 1 < NPG) ? (g + 1) : g;
        float dt_n[PG], xc_n[PG];
#pragma unroll
        for (int j = 0; j < PG; ++j) {
            int i = gg * PG + j;
            dt_n[j] = dtp[dstep * i];
            xc_n[j] = xcp[xstep * i];
        }
#pragma unroll
        for (int j = 0; j < PG; ++j) {
            int i = g * PG + j;
            float dtv = dt_r[j];
            float e = dtv * xc_r[j];
#pragma unroll
            for (int s = 0; s < 16; ++s) {
                float da = __builtin_amdgcn_exp2f(dtv * Acs[s]);
                h[s] = fmaf(da, h[s], e * Bs[i][s]);
                P[s] *= da;
            }
        }
#pragma unroll
        for (int j = 0; j < PG; ++j) { dt_r[j] = dt_n[j]; xc_r[j] = xc_n[j]; }
    }

    size_t o = ((size_t)(b * NCH + ch) * 1024 + c) * 16;
#pragma unroll
    for (int q = 0; q < 4; ++q) {
        *(float4*)&chP[o + q * 4] = make_float4(P[q*4], P[q*4+1], P[q*4+2], P[q*4+3]);
        *(float4*)&chH[o + q * 4] = make_float4(h[q*4], h[q*4+1], h[q*4+2], h[q*4+3]);
    }
}

__global__ __launch_bounds__(256)
void scan_p2(const float* __restrict__ chP,
             const float* __restrict__ chH,
             float* __restrict__ hst)
{
    int idx = blockIdx.x * 256 + threadIdx.x;   // B_SZ*16384
    int b  = idx >> 14;
    int cs = idx & 16383;
    float h = 0.f;
#pragma unroll
    for (int ch = 0; ch < NCH; ++ch) {
        size_t o = ((size_t)(b * NCH + ch) << 14) + cs;
        hst[o] = h;
        h = fmaf(chP[o], h, chH[o]);
    }
}

__global__ __launch_bounds__(256)
void scan_p3(const float* __restrict__ xdblP,
             const float* __restrict__ xc,
             const float* __restrict__ xz,    // z at col 1024+c (read only)
             const float* __restrict__ A_log,
             const float* __restrict__ Dp,
             const float* __restrict__ hst,
             short* __restrict__ ybarb, int rev)
{
    __shared__ float Bs[CHUNK][16];
    __shared__ float Cs[CHUNK][16];
    const int tid = threadIdx.x;
    const int blk = blockIdx.x;
    const int cb = blk & 3;
    const int ch = (blk >> 2) & (NCH - 1);
    const int b  = blk >> 6;
    const int c  = cb * 256 + tid;

    const int u0 = rev ? (SEQ - 1 - ch * CHUNK) : (ch * CHUNK);
    const int st = rev ? -1 : 1;

    for (int r = tid; r < CHUNK * 16; r += 256) {
        int i = r >> 4, s = r & 15;
        int row = b * SEQ + u0 + st * i;
        Bs[i][s] = xdblP[(size_t)row * NC_PAD + 1024 + s];
        Cs[i][s] = xdblP[(size_t)row * NC_PAD + 1040 + s];
    }

    float Acs[16];
#pragma unroll
    for (int s = 0; s < 16; ++s)
        Acs[s] = -__expf(A_log[c * 16 + s]) * 1.44269504f;

    const float Dc = Dp[c];

    float h[16];
    size_t o = ((size_t)(b * NCH + ch) * 1024 + c) * 16;
#pragma unroll
    for (int q = 0; q < 4; ++q) {
        float4 hv = *(const float4*)&hst[o + q * 4];
        h[q*4] = hv.x; h[q*4+1] = hv.y; h[q*4+2] = hv.z; h[q*4+3] = hv.w;
    }

    __syncthreads();

    const float* dtp = xdblP + (size_t)(b * SEQ + u0) * NC_PAD + c;
    const float* xcp = xc    + (size_t)(b * SEQ + u0) * D_INNER + c;
    const float* zp  = xz    + (size_t)(b * SEQ + u0) * (2 * D_INNER) + D_INNER + c;
    short*       yp  = ybarb + (size_t)(b * SEQ + u0) * D_INNER + c;
    const ptrdiff_t dstep = (ptrdiff_t)st * NC_PAD;
    const ptrdiff_t xstep = (ptrdiff_t)st * D_INNER;
    const ptrdiff_t zstep = (ptrdiff_t)st * 2 * D_INNER;

    float dt_r[PG], xc_r[PG], z_r[PG];
#pragma unroll
    for (int j = 0; j < PG; ++j) {
        dt_r[j] = dtp[dstep * j];
        xc_r[j] = xcp[xstep * j];
        z_r[j]  = zp[zstep * j];
    }

#pragma unroll 1
    for (int g = 0; g < NPG; ++g) {
        const int gg = (g + 1 < NPG) ? (g + 1) : g;
        float dt_n[PG], xc_n[PG], z_n[PG];
#pragma unroll
        for (int j = 0; j < PG; ++j) {
            int i = gg * PG + j;
            dt_n[j] = dtp[dstep * i];
            xc_n[j] = xcp[xstep * i];
            z_n[j]  = zp[zstep * i];
        }
#pragma unroll
        for (int j = 0; j < PG; ++j) {
            int i = g * PG + j;
            float dtv = dt_r[j];
            float xcv = xc_r[j];
            float e = dtv * xcv;
            float y = 0.f;
#pragma unroll
            for (int s = 0; s < 16; ++s) {
                float da = __builtin_amdgcn_exp2f(dtv * Acs[s]);
                h[s] = fmaf(da, h[s], e * Bs[i][s]);
                y = fmaf(h[s], Cs[i][s], y);
            }
            y = fmaf(Dc, xcv, y);
            float zv = z_r[j];
            float sig = 1.f / (1.f + __expf(-zv));
            yp[xstep * i] = f2bf(y * zv * sig);
        }
#pragma unroll
        for (int j = 0; j < PG; ++j) {
            dt_r[j] = dt_n[j]; xc_r[j] = xc_n[j]; z_r[j] = z_n[j];
        }
    }
}

extern "C" void kernel_launch(void* const* d_in, const int* in_sizes, int n_in,
                              void* d_out, int out_size, void* d_ws, size_t ws_size,
                              hipStream_t stream)
{
    const float* x = (const float*)d_in[0];
    float* out = (float*)d_out;
    float* ws  = (float*)d_ws;

    // workspace layout, 22,872,064 floats = 91.49 MB (< proven 92.27 MB)
    float* xz    = ws;                                    // 8,388,608
    float* xc    = xz    + 8388608;                       // 4,194,304
    float* xdblP = xc    + 4194304;                       // 4,718,592
    float* chP   = xdblP + 4718592;                       // 524,288
    float* chH   = chP   + 524288;                        // 524,288
    float* wreg  = chH   + 524288;                        // 589,824 (Wcb/hst)
    short* Wcb   = (short*)wreg;                          // 1,179,648 bf16
    float* hst   = wreg;   // alias: written by scan_p2 AFTER GEMM2 read Wcb
    float* f1    = wreg + 589824;
    short* xbf   = (short*)f1;                            // 1,048,576 fl region
    float* f2    = f1 + 1048576;
    short* in_wb = (short*)f2;                            // 524,288 fl region
    float* f3    = f2 + 524288;
    short* out_wb= (short*)f3;                            // 262,144 fl region
    float* f4    = f3 + 262144;
    short* xcb   = (short*)f4;                            // 2,097,152 fl region
    short* ybarb = xcb;    // alias: written by scan_p3 AFTER GEMM2 read xcb

    const int elemN = NTOK * D_INNER;
    const int gElem = (elemN + 255) / 256;
    const int gScan = B_SZ * NCH * 4;   // 128 blocks

    // x -> bf16 once (shared by both directions)
    cvt_bf16<<<(NTOK * DIM / 8 + 255) / 256, 256, 0, stream>>>(x, xbf, NTOK * DIM);

    for (int dir = 0; dir < 2; ++dir) {
        const float* in_w    = (const float*)d_in[1 + dir * 9 + 0];
        const float* conv_w  = (const float*)d_in[1 + dir * 9 + 1];
        const float* conv_b  = (const float*)d_in[1 + dir * 9 + 2];
        const float* xproj_w = (const float*)d_in[1 + dir * 9 + 3];
        const float* dt_w    = (const float*)d_in[1 + dir * 9 + 4];
        const float* dt_b    = (const float*)d_in[1 + dir * 9 + 5];
        const float* A_log   = (const float*)d_in[1 + dir * 9 + 6];
        const float* Dp      = (const float*)d_in[1 + dir * 9 + 7];
        const float* out_w   = (const float*)d_in[1 + dir * 9 + 8];

        // 0) weight prep (bf16)
        build_wc<<<(NC_PAD * D_INNER + 255) / 256, 256, 0, stream>>>(
            xproj_w, dt_w, Wcb);
        cvt_bf16<<<(2 * D_INNER * DIM / 8 + 255) / 256, 256, 0, stream>>>(
            in_w, in_wb, 2 * D_INNER * DIM);
        cvt_bf16<<<(DIM * D_INNER / 8 + 255) / 256, 256, 0, stream>>>(
            out_w, out_wb, DIM * D_INNER);

        // 1) xz = x @ in_w.T   [4096, 2048], K=512 — grid 16x32
        {
            dim3 g(2 * D_INNER / TN, NTOK / TM);
            gemm_bf16<<<g, 256, 0, stream>>>(xbf, DIM, in_wb, DIM,
                                             xz, 2 * D_INNER, DIM, 1.f, 0);
        }
        // 2) conv + silu -> xc (fp32) + xcb (bf16)
        conv_silu_kernel<<<gElem, 256, 0, stream>>>(xz, conv_w, conv_b,
                                                    xc, xcb, dir);
        // 3+4) xdblP = xc @ Wc.T  [4096, 1152], K=1024 — grid 9x32
        {
            dim3 g(NC_PAD / TN, NTOK / TM);
            gemm_bf16<<<g, 256, 0, stream>>>(xcb, D_INNER, Wcb, D_INNER,
                                             xdblP, NC_PAD, D_INNER, 1.f, 0);
        }
        // 5) dt = softplus(dt_pre + dt_b)
        bias_softplus_kernel<<<gElem, 256, 0, stream>>>(xdblP, dt_b);
        // 6) chunked scan -> ybarb (bf16; overwrites xcb region, now dead)
        scan_p1<<<gScan, 256, 0, stream>>>(xdblP, xc, A_log, chP, chH, dir);
        scan_p2<<<(B_SZ * 16384) / 256, 256, 0, stream>>>(chP, chH, hst);
        scan_p3<<<gScan, 256, 0, stream>>>(xdblP, xc, xz, A_log, Dp, hst,
                                           ybarb, dir);
        // 7) out (+)= 0.5 * ybar @ out_w.T   [4096, 512], K=1024 — grid 4x32
        {
            dim3 g(DIM / TN, NTOK / TM);
            gemm_bf16<<<g, 256, 0, stream>>>(ybarb, D_INNER, out_wb, D_INNER,
                                             out, DIM, D_INNER, 0.5f, dir);
        }
    }
}

// Round 11
// 395.673 us; speedup vs baseline: 1.5395x; 1.1757x over previous
//
#include <hip/hip_runtime.h>
#include <hip/hip_bf16.h>
#include <math.h>

#define DIM      512
#define D_STATE  16
#define D_CONV   4
#define D_INNER  1024
#define DT_RANK  32
#define B_SZ     2
#define SEQ      2048
#define NTOK     (B_SZ * SEQ)   // 4096
#define CHUNK    64
#define NCH      (SEQ / CHUNK)  // 32
#define NC_PAD   1152           // 1024 dt + 32 BC + 96 pad
#define PG       8              // scan pipeline group size
#define NPG      (CHUNK / PG)   // 8

typedef __attribute__((ext_vector_type(8))) short bf16x8;
typedef __attribute__((ext_vector_type(4))) float f32x4;

__device__ __forceinline__ short f2bf(float f) {
    unsigned u = __float_as_uint(f);
    u += 0x7fffu + ((u >> 16) & 1u);
    return (short)(u >> 16);
}
__device__ __forceinline__ float bf2f(short v) {
    return __uint_as_float(((unsigned)(unsigned short)v) << 16);
}

// async global->LDS, 16B per lane; LDS dest is wave-uniform base + lane*16
__device__ __forceinline__ void gload16(const void* g, void* l) {
    __builtin_amdgcn_global_load_lds(
        (const __attribute__((address_space(1))) void*)g,
        (__attribute__((address_space(3))) void*)l,
        16, 0, 0);
}

// ---------------- fp32 -> bf16 bulk convert (n % 8 == 0) ------------------
__global__ __launch_bounds__(256)
void cvt_bf16(const float* __restrict__ src, short* __restrict__ dst, int n)
{
    int i = (blockIdx.x * 256 + threadIdx.x) * 8;
    if (i >= n) return;
    float4 a = *(const float4*)(src + i);
    float4 b = *(const float4*)(src + i + 4);
    bf16x8 v;
    v[0] = f2bf(a.x); v[1] = f2bf(a.y); v[2] = f2bf(a.z); v[3] = f2bf(a.w);
    v[4] = f2bf(b.x); v[5] = f2bf(b.y); v[6] = f2bf(b.z); v[7] = f2bf(b.w);
    *(bf16x8*)(dst + i) = v;
}

// ---------------- MFMA GEMM (bf16 operands): C (+)= alpha * A @ W^T ---------
// 128x128 tile, BK=32, 4 waves (2x2), wave tile 64x64 (4x4 frags 16x16x32).
// global_load_lds dwordx4 staging, double-buffered LDS (2-phase schedule).
#define TM 128
#define TN 128
#define TK 32

__global__ __launch_bounds__(256)
void gemm_bf16(const short* __restrict__ A, int lda,
               const short* __restrict__ W, int ldw,
               float* __restrict__ C, int ldc,
               int K, float alpha, int accum)
{
    __shared__ __align__(16) short As[2][TM * TK];
    __shared__ __align__(16) short Ws[2][TN * TK];

    const int tid  = threadIdx.x;
    const int lane = tid & 63;
    const int wid  = tid >> 6;
    const int wr   = wid >> 1, wc = wid & 1;
    const int m0 = blockIdx.y * TM;
    const int n0 = blockIdx.x * TN;

    const int am0 = ((tid >> 6) << 4) | (tid & 15);
    const int kc0 = (tid >> 4) & 3;
    const short* pa0 = A + (size_t)(m0 + am0) * lda + kc0 * 8;
    const short* pa1 = pa0 + (size_t)64 * lda;
    const short* pw0 = W + (size_t)(n0 + am0) * ldw + kc0 * 8;
    const short* pw1 = pw0 + (size_t)64 * ldw;

    f32x4 acc[4][4] = {};
    const int nt = K / TK;

    gload16(pa0, &As[0][tid * 8]);
    gload16(pa1, &As[0][(tid + 256) * 8]);
    gload16(pw0, &Ws[0][tid * 8]);
    gload16(pw1, &Ws[0][(tid + 256) * 8]);
    asm volatile("s_waitcnt vmcnt(0)" ::: "memory");
    __syncthreads();

    int cur = 0;
    for (int t = 0; t < nt; ++t) {
        if (t + 1 < nt) {
            const int off = (t + 1) * TK;
            gload16(pa0 + off, &As[cur ^ 1][tid * 8]);
            gload16(pa1 + off, &As[cur ^ 1][(tid + 256) * 8]);
            gload16(pw0 + off, &Ws[cur ^ 1][tid * 8]);
            gload16(pw1 + off, &Ws[cur ^ 1][(tid + 256) * 8]);
        }
        bf16x8 af[4], bff[4];
#pragma unroll
        for (int f = 0; f < 4; ++f) {
            int ai = (wr * 4 + f) * 64 + (lane >> 4) * 16 + (lane & 15);
            af[f]  = *(const bf16x8*)(&As[cur][ai * 8]);
            int bi = (wc * 4 + f) * 64 + (lane >> 4) * 16 + (lane & 15);
            bff[f] = *(const bf16x8*)(&Ws[cur][bi * 8]);
        }
#pragma unroll
        for (int i = 0; i < 4; ++i)
#pragma unroll
            for (int j = 0; j < 4; ++j)
                acc[i][j] = __builtin_amdgcn_mfma_f32_16x16x32_bf16(
                    af[i], bff[j], acc[i][j], 0, 0, 0);
        asm volatile("s_waitcnt vmcnt(0)" ::: "memory");
        __syncthreads();
        cur ^= 1;
    }

#pragma unroll
    for (int i = 0; i < 4; ++i) {
        int row = m0 + wr * 64 + i * 16 + ((lane >> 4) << 2);
#pragma unroll
        for (int j = 0; j < 4; ++j) {
            int col = n0 + wc * 64 + j * 16 + (lane & 15);
#pragma unroll
            for (int r = 0; r < 4; ++r) {
                float v = alpha * acc[i][j][r];
                float* p = &C[(size_t)(row + r) * ldc + col];
                if (accum) *p += v; else *p = v;
            }
        }
    }
}

// ---------------- combined projection weight (bf16 out) ------------------
__global__ __launch_bounds__(256)
void build_wc(const float* __restrict__ xproj_w,  // [64,1024]
              const float* __restrict__ dt_w,     // [1024,32]
              short* __restrict__ Wcb)            // [1152,1024] bf16
{
    int idx = blockIdx.x * 256 + threadIdx.x;
    if (idx >= NC_PAD * D_INNER) return;
    int i = idx >> 10, k = idx & 1023;
    float v;
    if (i < 1024) {
        v = 0.f;
#pragma unroll
        for (int r = 0; r < 32; ++r)
            v = fmaf(dt_w[i * 32 + r], xproj_w[r * 1024 + k], v);
    } else if (i < 1056) {
        v = xproj_w[(i - 1024 + 32) * 1024 + k];
    } else {
        v = 0.f;
    }
    Wcb[idx] = f2bf(v);
}

// ---------------- depthwise causal conv (k=4) + bias + SiLU --------------
// writes bf16 xcb only (GEMM2 operand and scan input)
__global__ __launch_bounds__(256)
void conv_silu_kernel(const float* __restrict__ xz,
                      const float* __restrict__ cw,
                      const float* __restrict__ cb,
                      short* __restrict__ xcb, int rev)
{
    int idx = blockIdx.x * 256 + threadIdx.x;
    if (idx >= NTOK * D_INNER) return;
    int c   = idx & (D_INNER - 1);
    int row = idx >> 10;
    int b   = row / SEQ;
    int u   = row - b * SEQ;

    float w0 = cw[c * 4 + 0], w1 = cw[c * 4 + 1];
    float w2 = cw[c * 4 + 2], w3 = cw[c * 4 + 3];
    float accv = cb[c];
    if (!rev) {
#pragma unroll
        for (int k = 0; k < 4; ++k) {
            int uu = u - 3 + k;
            float wv = (k == 0) ? w0 : (k == 1) ? w1 : (k == 2) ? w2 : w3;
            if (uu >= 0)
                accv = fmaf(wv, xz[(size_t)(b * SEQ + uu) * (2 * D_INNER) + c], accv);
        }
    } else {
#pragma unroll
        for (int k = 0; k < 4; ++k) {
            int uu = u + 3 - k;
            float wv = (k == 0) ? w0 : (k == 1) ? w1 : (k == 2) ? w2 : w3;
            if (uu < SEQ)
                accv = fmaf(wv, xz[(size_t)(b * SEQ + uu) * (2 * D_INNER) + c], accv);
        }
    }
    float r = accv / (1.f + expf(-accv));
    xcb[idx] = f2bf(r);
}

// ---------------- dt bias + softplus (in place, strided) -----------------
__global__ __launch_bounds__(256)
void bias_softplus_kernel(float* __restrict__ xdblP, const float* __restrict__ dtb)
{
    int idx = blockIdx.x * 256 + threadIdx.x;
    if (idx >= NTOK * D_INNER) return;
    int c = idx & (D_INNER - 1);
    int row = idx >> 10;
    float* p = &xdblP[(size_t)row * NC_PAD + c];
    float v = *p + dtb[c];
    *p = (v > 20.f) ? v : log1pf(expf(v));
}

// ---------------- chunked SSM scan: one thread per channel, h[16] in regs --
// grid: b (2) x ch (NCH) x cb (4) = 256 blocks; c = cb*256 + tid.
// summaries: chP/chH/hst[((b*NCH+ch)*1024 + c)*16 + s]
__global__ __launch_bounds__(256)
void scan_p1(const float* __restrict__ xdblP,
             const short* __restrict__ xcb,
             const float* __restrict__ A_log,
             float* __restrict__ chP,
             float* __restrict__ chH, int rev)
{
    __shared__ float Bs[CHUNK][16];
    const int tid = threadIdx.x;
    const int blk = blockIdx.x;
    const int cb = blk & 3;
    const int ch = (blk >> 2) & (NCH - 1);
    const int b  = blk / (4 * NCH);
    const int c  = cb * 256 + tid;

    const int u0 = rev ? (SEQ - 1 - ch * CHUNK) : (ch * CHUNK);
    const int st = rev ? -1 : 1;

    for (int r = tid; r < CHUNK * 16; r += 256) {
        int i = r >> 4, s = r & 15;
        int row = b * SEQ + u0 + st * i;
        Bs[i][s] = xdblP[(size_t)row * NC_PAD + 1024 + s];
    }

    float Acs[16];
#pragma unroll
    for (int s = 0; s < 16; ++s)
        Acs[s] = -__expf(A_log[c * 16 + s]) * 1.44269504f;

    float h[16], P[16];
#pragma unroll
    for (int s = 0; s < 16; ++s) { h[s] = 0.f; P[s] = 1.f; }

    __syncthreads();

    const float* dtp = xdblP + (size_t)(b * SEQ + u0) * NC_PAD + c;
    const short* xcp = xcb   + (size_t)(b * SEQ + u0) * D_INNER + c;
    const ptrdiff_t dstep = (ptrdiff_t)st * NC_PAD;
    const ptrdiff_t xstep = (ptrdiff_t)st * D_INNER;

    float dt_r[PG], xc_r[PG];
#pragma unroll
    for (int j = 0; j < PG; ++j) {
        dt_r[j] = dtp[dstep * j];
        xc_r[j] = bf2f(xcp[xstep * j]);
    }

#pragma unroll 1
    for (int g = 0; g < NPG; ++g) {
        const int gg = (g + 1 < NPG) ? (g + 1) : g;
        float dt_n[PG], xc_n[PG];
#pragma unroll
        for (int j = 0; j < PG; ++j) {
            int i = gg * PG + j;
            dt_n[j] = dtp[dstep * i];
            xc_n[j] = bf2f(xcp[xstep * i]);
        }
#pragma unroll
        for (int j = 0; j < PG; ++j) {
            int i = g * PG + j;
            float dtv = dt_r[j];
            float e = dtv * xc_r[j];
#pragma unroll
            for (int s = 0; s < 16; ++s) {
                float da = __builtin_amdgcn_exp2f(dtv * Acs[s]);
                h[s] = fmaf(da, h[s], e * Bs[i][s]);
                P[s] *= da;
            }
        }
#pragma unroll
        for (int j = 0; j < PG; ++j) { dt_r[j] = dt_n[j]; xc_r[j] = xc_n[j]; }
    }

    size_t o = ((size_t)(b * NCH + ch) * 1024 + c) * 16;
#pragma unroll
    for (int q = 0; q < 4; ++q) {
        *(float4*)&chP[o + q * 4] = make_float4(P[q*4], P[q*4+1], P[q*4+2], P[q*4+3]);
        *(float4*)&chH[o + q * 4] = make_float4(h[q*4], h[q*4+1], h[q*4+2], h[q*4+3]);
    }
}

__global__ __launch_bounds__(256)
void scan_p2(const float* __restrict__ chP,
             const float* __restrict__ chH,
             float* __restrict__ hst)
{
    int idx = blockIdx.x * 256 + threadIdx.x;   // B_SZ*16384
    int b  = idx >> 14;
    int cs = idx & 16383;
    float h = 0.f;
#pragma unroll
    for (int ch = 0; ch < NCH; ++ch) {
        size_t o = ((size_t)(b * NCH + ch) << 14) + cs;
        hst[o] = h;
        h = fmaf(chP[o], h, chH[o]);
    }
}

__global__ __launch_bounds__(256)
void scan_p3(const float* __restrict__ xdblP,
             const short* __restrict__ xcb,
             const float* __restrict__ xz,    // z at col 1024+c (read only)
             const float* __restrict__ A_log,
             const float* __restrict__ Dp,
             const float* __restrict__ hst,
             short* __restrict__ ybarb, int rev)
{
    __shared__ float Bs[CHUNK][16];
    __shared__ float Cs[CHUNK][16];
    const int tid = threadIdx.x;
    const int blk = blockIdx.x;
    const int cb = blk & 3;
    const int ch = (blk >> 2) & (NCH - 1);
    const int b  = blk / (4 * NCH);
    const int c  = cb * 256 + tid;

    const int u0 = rev ? (SEQ - 1 - ch * CHUNK) : (ch * CHUNK);
    const int st = rev ? -1 : 1;

    for (int r = tid; r < CHUNK * 16; r += 256) {
        int i = r >> 4, s = r & 15;
        int row = b * SEQ + u0 + st * i;
        Bs[i][s] = xdblP[(size_t)row * NC_PAD + 1024 + s];
        Cs[i][s] = xdblP[(size_t)row * NC_PAD + 1040 + s];
    }

    float Acs[16];
#pragma unroll
    for (int s = 0; s < 16; ++s)
        Acs[s] = -__expf(A_log[c * 16 + s]) * 1.44269504f;

    const float Dc = Dp[c];

    float h[16];
    size_t o = ((size_t)(b * NCH + ch) * 1024 + c) * 16;
#pragma unroll
    for (int q = 0; q < 4; ++q) {
        float4 hv = *(const float4*)&hst[o + q * 4];
        h[q*4] = hv.x; h[q*4+1] = hv.y; h[q*4+2] = hv.z; h[q*4+3] = hv.w;
    }

    __syncthreads();

    const float* dtp = xdblP + (size_t)(b * SEQ + u0) * NC_PAD + c;
    const short* xcp = xcb   + (size_t)(b * SEQ + u0) * D_INNER + c;
    const float* zp  = xz    + (size_t)(b * SEQ + u0) * (2 * D_INNER) + D_INNER + c;
    short*       yp  = ybarb + (size_t)(b * SEQ + u0) * D_INNER + c;
    const ptrdiff_t dstep = (ptrdiff_t)st * NC_PAD;
    const ptrdiff_t xstep = (ptrdiff_t)st * D_INNER;
    const ptrdiff_t zstep = (ptrdiff_t)st * 2 * D_INNER;

    float dt_r[PG], xc_r[PG], z_r[PG];
#pragma unroll
    for (int j = 0; j < PG; ++j) {
        dt_r[j] = dtp[dstep * j];
        xc_r[j] = bf2f(xcp[xstep * j]);
        z_r[j]  = zp[zstep * j];
    }

#pragma unroll 1
    for (int g = 0; g < NPG; ++g) {
        const int gg = (g + 1 < NPG) ? (g + 1) : g;
        float dt_n[PG], xc_n[PG], z_n[PG];
#pragma unroll
        for (int j = 0; j < PG; ++j) {
            int i = gg * PG + j;
            dt_n[j] = dtp[dstep * i];
            xc_n[j] = bf2f(xcp[xstep * i]);
            z_n[j]  = zp[zstep * i];
        }
#pragma unroll
        for (int j = 0; j < PG; ++j) {
            int i = g * PG + j;
            float dtv = dt_r[j];
            float xcv = xc_r[j];
            float e = dtv * xcv;
            float y = 0.f;
#pragma unroll
            for (int s = 0; s < 16; ++s) {
                float da = __builtin_amdgcn_exp2f(dtv * Acs[s]);
                h[s] = fmaf(da, h[s], e * Bs[i][s]);
                y = fmaf(h[s], Cs[i][s], y);
            }
            y = fmaf(Dc, xcv, y);
            float zv = z_r[j];
            float sig = 1.f / (1.f + __expf(-zv));
            yp[xstep * i] = f2bf(y * zv * sig);
        }
#pragma unroll
        for (int j = 0; j < PG; ++j) {
            dt_r[j] = dt_n[j]; xc_r[j] = xc_n[j]; z_r[j] = z_n[j];
        }
    }
}

extern "C" void kernel_launch(void* const* d_in, const int* in_sizes, int n_in,
                              void* d_out, int out_size, void* d_ws, size_t ws_size,
                              hipStream_t stream)
{
    const float* x = (const float*)d_in[0];
    float* out = (float*)d_out;
    float* ws  = (float*)d_ws;

    // workspace layout, 20,774,912 floats = 83.1 MB (< proven 92.27 MB)
    float* xz    = ws;                                    // 8,388,608
    float* xdblP = xz    + 8388608;                       // 4,718,592
    float* chP   = xdblP + 4718592;                       // 1,048,576
    float* chH   = chP   + 1048576;                       // 1,048,576
    float* hst   = chH   + 1048576;                       // 1,048,576
    float* f0    = hst   + 1048576;
    short* Wcb   = (short*)f0;                            // 589,824 fl region
    float* f1    = f0 + 589824;
    short* xbf   = (short*)f1;                            // 1,048,576 fl region
    float* f2    = f1 + 1048576;
    short* in_wb = (short*)f2;                            // 524,288 fl region
    float* f3    = f2 + 524288;
    short* out_wb= (short*)f3;                            // 262,144 fl region
    float* f4    = f3 + 262144;
    short* xcb   = (short*)f4;                            // 2,097,152 fl region
    short* ybarb = xcb;    // alias: written by scan_p3 AFTER GEMM2 read xcb

    const int elemN = NTOK * D_INNER;
    const int gElem = (elemN + 255) / 256;
    const int gScan = B_SZ * NCH * 4;   // 256 blocks

    // x -> bf16 once (shared by both directions)
    cvt_bf16<<<(NTOK * DIM / 8 + 255) / 256, 256, 0, stream>>>(x, xbf, NTOK * DIM);

    for (int dir = 0; dir < 2; ++dir) {
        const float* in_w    = (const float*)d_in[1 + dir * 9 + 0];
        const float* conv_w  = (const float*)d_in[1 + dir * 9 + 1];
        const float* conv_b  = (const float*)d_in[1 + dir * 9 + 2];
        const float* xproj_w = (const float*)d_in[1 + dir * 9 + 3];
        const float* dt_w    = (const float*)d_in[1 + dir * 9 + 4];
        const float* dt_b    = (const float*)d_in[1 + dir * 9 + 5];
        const float* A_log   = (const float*)d_in[1 + dir * 9 + 6];
        const float* Dp      = (const float*)d_in[1 + dir * 9 + 7];
        const float* out_w   = (const float*)d_in[1 + dir * 9 + 8];

        // 0) weight prep (bf16)
        build_wc<<<(NC_PAD * D_INNER + 255) / 256, 256, 0, stream>>>(
            xproj_w, dt_w, Wcb);
        cvt_bf16<<<(2 * D_INNER * DIM / 8 + 255) / 256, 256, 0, stream>>>(
            in_w, in_wb, 2 * D_INNER * DIM);
        cvt_bf16<<<(DIM * D_INNER / 8 + 255) / 256, 256, 0, stream>>>(
            out_w, out_wb, DIM * D_INNER);

        // 1) xz = x @ in_w.T   [4096, 2048], K=512 — grid 16x32
        {
            dim3 g(2 * D_INNER / TN, NTOK / TM);
            gemm_bf16<<<g, 256, 0, stream>>>(xbf, DIM, in_wb, DIM,
                                             xz, 2 * D_INNER, DIM, 1.f, 0);
        }
        // 2) conv + silu -> xcb (bf16)
        conv_silu_kernel<<<gElem, 256, 0, stream>>>(xz, conv_w, conv_b,
                                                    xcb, dir);
        // 3+4) xdblP = xc @ Wc.T  [4096, 1152], K=1024 — grid 9x32
        {
            dim3 g(NC_PAD / TN, NTOK / TM);
            gemm_bf16<<<g, 256, 0, stream>>>(xcb, D_INNER, Wcb, D_INNER,
                                             xdblP, NC_PAD, D_INNER, 1.f, 0);
        }
        // 5) dt = softplus(dt_pre + dt_b)
        bias_softplus_kernel<<<gElem, 256, 0, stream>>>(xdblP, dt_b);
        // 6) chunked scan -> ybarb (bf16; overwrites xcb region, now dead)
        scan_p1<<<gScan, 256, 0, stream>>>(xdblP, xcb, A_log, chP, chH, dir);
        scan_p2<<<(B_SZ * 16384) / 256, 256, 0, stream>>>(chP, chH, hst);
        scan_p3<<<gScan, 256, 0, stream>>>(xdblP, xcb, xz, A_log, Dp, hst,
                                           ybarb, dir);
        // 7) out (+)= 0.5 * ybar @ out_w.T   [4096, 512], K=1024 — grid 4x32
        {
            dim3 g(DIM / TN, NTOK / TM);
            gemm_bf16<<<g, 256, 0, stream>>>(ybarb, D_INNER, out_wb, D_INNER,
                                             out, DIM, D_INNER, 0.5f, dir);
        }
    }
}